// Round 1
// baseline (137.946 us; speedup 1.0000x reference)
//
#include <hip/hip_runtime.h>
#include <stdint.h>

// ContrastiveLossInBatch: loss = mean_i [ lse_j(q_i.k_j/T) - q_i.k_i/T ],
// N=8192, C=256, T=0.07. Fused f16-MFMA GEMM + per-lane online logsumexp.
//
// R1 theory: previous version was LDS-read bound (1 KiB B-frag per MFMA,
// 2.15 GB LDS reads = ~31 us wall vs 16.6 us MFMA floor; MfmaUtil 28%).
// Now each wave owns 64 rows (A resident in 128 VGPRs), so each B-fragment
// feeds 4 MFMAs -> LDS traffic /4 (537 MB). LDS double-buffered (64 KiB),
// stage(jt+1) issued before compute(jt), ONE barrier per tile. Diagonal
// computed in cvt_kernel (wave == one row) to drop P state from the GEMM.
//
// Workspace layout (9 MiB + 32 KiB + 128 B):
//   [0,       4 MiB)  q in f16, pre-scaled by (1/T)*log2(e)
//   [4 MiB,   8 MiB)  k in f16
//   [8 MiB, +512 KiB) per-(split,row) running max M   (SPLIT*N floats)
//   ...     +512 KiB  per-(split,row) running sum S
//   ...     +32 KiB   per-row diagonal (base-2 units)
//   ...               32 partial row-loss sums

#define N_ROWS 8192
#define C_DIM  256
#define BN     64
#define SPLIT  16
#define JCOLS  (N_ROWS / SPLIT)   // 512 columns per split
#define JTILES (JCOLS / BN)       // 8 k-tiles per block
#define RF     4                  // 16-row A fragments per wave (64 rows/wave)
#define BLK_ROWS 256              // 4 waves * 64 rows

typedef __attribute__((ext_vector_type(8))) _Float16 half8;
typedef __attribute__((ext_vector_type(4))) _Float16 half4;
typedef __attribute__((ext_vector_type(4))) float    f32x4;

#if __has_builtin(__builtin_amdgcn_exp2f)
#define EXP2(x) __builtin_amdgcn_exp2f(x)
#else
#define EXP2(x) exp2f(x)
#endif
#if __has_builtin(__builtin_amdgcn_logf)
#define LOG2(x) __builtin_amdgcn_logf(x)
#else
#define LOG2(x) log2f(x)
#endif

__device__ __forceinline__ void gload_lds16(const void* g, void* l) {
  __builtin_amdgcn_global_load_lds(
      (const __attribute__((address_space(1))) unsigned int*)g,
      (__attribute__((address_space(3))) unsigned int*)l, 16, 0, 0);
}

// ---- fp32 -> f16 conversion + per-row diagonal -----------------------------
// One wave covers exactly one row (64 lanes x 4 elems = 256 = C), so the
// diagonal q_i.k_i (f16-rounded operands, f32 accum — same regime as the
// MFMA diag it replaces) is a free wave-reduce here.
__global__ void cvt_kernel(const float* __restrict__ q, const float* __restrict__ k,
                           _Float16* __restrict__ qh, _Float16* __restrict__ kh,
                           float* __restrict__ pP) {
  const float QS = 20.60992915555663f;  // (1/0.07) * log2(e)
  int i = blockIdx.x * 256 + threadIdx.x;
  float4 qv = ((const float4*)q)[i];
  float4 kv = ((const float4*)k)[i];
  half4 qo, ko;
  qo[0] = (_Float16)(qv.x * QS); qo[1] = (_Float16)(qv.y * QS);
  qo[2] = (_Float16)(qv.z * QS); qo[3] = (_Float16)(qv.w * QS);
  ko[0] = (_Float16)kv.x; ko[1] = (_Float16)kv.y;
  ko[2] = (_Float16)kv.z; ko[3] = (_Float16)kv.w;
  ((half4*)qh)[i] = qo;
  ((half4*)kh)[i] = ko;

  float d = (float)qo[0] * (float)ko[0];
  d = fmaf((float)qo[1], (float)ko[1], d);
  d = fmaf((float)qo[2], (float)ko[2], d);
  d = fmaf((float)qo[3], (float)ko[3], d);
#pragma unroll
  for (int off = 1; off < 64; off <<= 1) d += __shfl_xor(d, off);
  if ((threadIdx.x & 63) == 0) pP[i >> 6] = d;   // row = global_thread / 64
}

// ---- main fused GEMM + per-lane online base-2 logsumexp --------------------
// Block: 256 threads = 4 waves; wave w owns 64 rows (4 x 16-row fragments,
// q resident in VGPRs for the whole kernel). k-tile (64x256 f16 = 32 KiB)
// double-buffered in LDS; stage(jt+1) issued before compute(jt) so the
// barrier's vmcnt drain is fully hidden. Each B-fragment ds_read feeds 4
// MFMAs (one per row fragment). acc processed two col-frags at a time to
// keep VGPR < 256 (2 waves/SIMD).
__launch_bounds__(256, 2)
__global__ void sim_lse_kernel(const _Float16* __restrict__ qh,
                               const _Float16* __restrict__ kh,
                               float* __restrict__ pM,
                               float* __restrict__ pS) {
  __shared__ __align__(16) _Float16 kt[2 * BN * C_DIM];  // 64 KiB (2 buffers)
  const int tid  = threadIdx.x;
  const int lane = tid & 63;
  const int wave = tid >> 6;
  const int l15  = lane & 15;
  const int lg   = lane >> 4;       // quad group 0..3

  const int rb   = blockIdx.x;      // row block 0..31
  const int sp   = blockIdx.y;      // column split 0..15
  const int row0 = rb * BLK_ROWS + wave * 64;

  // A fragments: lane holds q[row0 + rf*16 + l15][ks*32 + lg*8 .. +8)
  half8 a[RF][8];
#pragma unroll
  for (int rf = 0; rf < RF; ++rf) {
    const _Float16* qr = qh + (size_t)(row0 + rf * 16 + l15) * C_DIM + lg * 8;
#pragma unroll
    for (int f = 0; f < 8; ++f) a[rf][f] = *(const half8*)(qr + f * 32);
  }

  // Per-lane LSE state: slot (rf, r) = row row0 + rf*16 + lg*4 + r,
  // columns {cf*16 + l15 : cf, per tile}
  float M[RF][4], S[RF][4];
#pragma unroll
  for (int rf = 0; rf < RF; ++rf)
#pragma unroll
    for (int r = 0; r < 4; ++r) { M[rf][r] = -__builtin_inff(); S[rf][r] = 0.f; }

  // swizzled LDS base per col-frag: addr = bbase[cf] ^ (ks*64)
  int bbase[4];
#pragma unroll
  for (int cf = 0; cf < 4; ++cf) {
    int nl = cf * 16 + l15;
    bbase[cf] = nl * 512 + (((nl & 31) * 16) ^ (lg * 16));
  }

  const char* ksrc = (const char*)(kh + (size_t)sp * JCOLS * C_DIM);
  char* lds = (char*)kt;

  // ---- prologue: stage tile 0 into buffer 0 (swizzled source, linear dest)
#pragma unroll
  for (int it = 0; it < 8; ++it) {
    int linear = it * 4096 + tid * 16;
    int row = linear >> 9;                      // 512 B per k row
    int gc  = ((linear >> 4) & 31) ^ (row & 31);
    gload_lds16(ksrc + row * 512 + gc * 16, lds + linear);
  }

#pragma unroll 2
  for (int jt = 0; jt < JTILES; ++jt) {
    __syncthreads();  // tile jt staged (vmcnt drained) & prev buffer consumed
    const char* cur = lds + (jt & 1) * 32768;

    // issue next tile's loads NOW; they complete during compute below
    if (jt + 1 < JTILES) {
      const char* src = ksrc + (size_t)(jt + 1) * (BN * C_DIM * 2);
      char* nxt = lds + ((jt + 1) & 1) * 32768;
#pragma unroll
      for (int it = 0; it < 8; ++it) {
        int linear = it * 4096 + tid * 16;
        int row = linear >> 9;
        int gc  = ((linear >> 4) & 31) ^ (row & 31);
        gload_lds16(src + row * 512 + gc * 16, nxt + linear);
      }
    }

    // ---- 64-col tile, two col-frags at a time (acc = 32 VGPR live) -------
#pragma unroll
    for (int cp = 0; cp < 2; ++cp) {
      f32x4 acc0[RF], acc1[RF];
#pragma unroll
      for (int rf = 0; rf < RF; ++rf) {
        f32x4 z = {0.f, 0.f, 0.f, 0.f};
        acc0[rf] = z; acc1[rf] = z;
      }
      const int b0off = bbase[cp * 2];
      const int b1off = bbase[cp * 2 + 1];
#pragma unroll
      for (int ks = 0; ks < 8; ++ks) {
        half8 b0 = *(const half8*)(cur + (b0off ^ (ks * 64)));
        half8 b1 = *(const half8*)(cur + (b1off ^ (ks * 64)));
#pragma unroll
        for (int rf = 0; rf < RF; ++rf) {
          acc0[rf] = __builtin_amdgcn_mfma_f32_16x16x32_f16(a[rf][ks], b0, acc0[rf], 0, 0, 0);
          acc1[rf] = __builtin_amdgcn_mfma_f32_16x16x32_f16(a[rf][ks], b1, acc1[rf], 0, 0, 0);
        }
      }
      // per-lane online logsumexp (base 2), no cross-lane traffic
#pragma unroll
      for (int rf = 0; rf < RF; ++rf)
#pragma unroll
        for (int r = 0; r < 4; ++r) {
          float v0 = acc0[rf][r], v1 = acc1[rf][r];
          float tmax  = fmaxf(v0, v1);
          float newM  = fmaxf(M[rf][r], tmax);
          float alpha = EXP2(M[rf][r] - newM);      // exp2(-inf)=0 handles init
          float p = EXP2(v0 - newM) + EXP2(v1 - newM);
          S[rf][r] = fmaf(S[rf][r], alpha, p);
          M[rf][r] = newM;
        }
    }
  }

  // ---- one-time 16-lane butterfly merge of (M,S) --------------------------
#pragma unroll
  for (int rf = 0; rf < RF; ++rf)
#pragma unroll
    for (int r = 0; r < 4; ++r) {
#pragma unroll
      for (int off = 1; off < 16; off <<= 1) {
        float Mo = __shfl_xor(M[rf][r], off);
        float So = __shfl_xor(S[rf][r], off);
        float nm = fmaxf(M[rf][r], Mo);
        S[rf][r] = S[rf][r] * EXP2(M[rf][r] - nm) + So * EXP2(Mo - nm);
        M[rf][r] = nm;
      }
    }

  if (l15 == 0) {
#pragma unroll
    for (int rf = 0; rf < RF; ++rf)
#pragma unroll
      for (int r = 0; r < 4; ++r) {
        int grow = row0 + rf * 16 + lg * 4 + r;
        pM[(size_t)sp * N_ROWS + grow] = M[rf][r];
        pS[(size_t)sp * N_ROWS + grow] = S[rf][r];
      }
  }
}

// ---- stage 1: 32 blocks, one thread per row; partial sums -----------------
__global__ void finish1_kernel(const float* __restrict__ pM, const float* __restrict__ pS,
                               const float* __restrict__ pP, float* __restrict__ pPart) {
  const int tid = threadIdx.x;
  const int r = blockIdx.x * 256 + tid;
  float m = -__builtin_inff();
#pragma unroll
  for (int s = 0; s < SPLIT; ++s) m = fmaxf(m, pM[s * N_ROWS + r]);
  float ssum = 0.f;
#pragma unroll
  for (int s = 0; s < SPLIT; ++s)
    ssum = fmaf(pS[s * N_ROWS + r], EXP2(pM[s * N_ROWS + r] - m), ssum);
  float accl = (m + LOG2(ssum)) - pP[r];   // row loss in base-2 units
#pragma unroll
  for (int off = 1; off < 64; off <<= 1) accl += __shfl_xor(accl, off);
  __shared__ float wsum[4];
  if ((tid & 63) == 0) wsum[tid >> 6] = accl;
  __syncthreads();
  if (tid == 0)
    pPart[blockIdx.x] = wsum[0] + wsum[1] + wsum[2] + wsum[3];
}

// ---- stage 2: reduce 32 partials, convert base-2 -> nats, mean ------------
__global__ void finish2_kernel(const float* __restrict__ pPart, float* __restrict__ out) {
  const int tid = threadIdx.x;   // 64 threads
  float v = (tid < 32) ? pPart[tid] : 0.f;
#pragma unroll
  for (int off = 1; off < 64; off <<= 1) v += __shfl_xor(v, off);
  if (tid == 0)
    out[0] = v * (0.69314718055994531f / (float)N_ROWS);  // ln2 * mean
}

extern "C" void kernel_launch(void* const* d_in, const int* in_sizes, int n_in,
                              void* d_out, int out_size, void* d_ws, size_t ws_size,
                              hipStream_t stream) {
  const float* q = (const float*)d_in[0];
  const float* k = (const float*)d_in[1];
  float* out = (float*)d_out;
  char* ws = (char*)d_ws;

  _Float16* qh = (_Float16*)ws;                                  // 4 MiB
  _Float16* kh = (_Float16*)(ws + (size_t)N_ROWS * C_DIM * 2);   // 4 MiB
  float* pM = (float*)(ws + (size_t)N_ROWS * C_DIM * 4);         // 512 KiB
  float* pS = pM + SPLIT * N_ROWS;                               // 512 KiB
  float* pP = pS + SPLIT * N_ROWS;                               // 32 KiB
  float* pPart = pP + N_ROWS;                                    // 128 B

  cvt_kernel<<<dim3(N_ROWS * C_DIM / 4 / 256), dim3(256), 0, stream>>>(q, k, qh, kh, pP);
  sim_lse_kernel<<<dim3(N_ROWS / BLK_ROWS, SPLIT), dim3(256), 0, stream>>>(qh, kh, pM, pS);
  finish1_kernel<<<dim3(N_ROWS / 256), dim3(256), 0, stream>>>(pM, pS, pP, pPart);
  finish2_kernel<<<dim3(1), dim3(64), 0, stream>>>(pPart, out);
}

// Round 2
// 116.015 us; speedup vs baseline: 1.1890x; 1.1890x over previous
//
#include <hip/hip_runtime.h>
#include <stdint.h>

// ContrastiveLossInBatch: loss = mean_i [ lse_j(q_i.k_j/T) - q_i.k_i/T ],
// N=8192, C=256, T=0.07. Fused MFMA GEMM + per-lane online logsumexp (base 2).
//
// R2: R1's RF=4 16x16 attempt spilled (VGPR capped at 128, 49 MB scratch
// writes). Same LDS-traffic goal via mfma_f32_32x32x16_f16 instead: one 16B
// B-fragment per lane feeds 32768 FLOP (2x the 16x16x32 rate), so LDS reads
// halve vs R0 (2.15 GB -> 1.07 GB ~ 13.7 us) and match the 13.8 us MFMA
// floor. Wave owns 32 rows; A = 16 x half8 = 64 VGPR resident; dual 32-col
// accumulators (32 VGPR); est ~160 VGPR total -> no spill at 2 waves/SIMD.
// Double-buffered LDS (64 KiB), stage(jt+1) issued before compute(jt), ONE
// barrier per tile. Diagonal comes from cvt_kernel. sp = bid&7 pins each
// column-split's 512 KiB k-slice to one XCD's L2.
//
// Workspace layout (8.5 MiB + 32 KiB + 128 B):
//   [0,       4 MiB)  q in f16, pre-scaled by (1/T)*log2(e)
//   [4 MiB,   8 MiB)  k in f16
//   [8 MiB, +256 KiB) per-(split,row) running max M   (SPLIT*N floats)
//   ...     +256 KiB  per-(split,row) running sum S
//   ...     +32 KiB   per-row diagonal (base-2 units)
//   ...               32 partial row-loss sums

#define N_ROWS 8192
#define C_DIM  256
#define BN     64
#define SPLIT  8
#define JCOLS  (N_ROWS / SPLIT)   // 1024 columns per split
#define JTILES (JCOLS / BN)       // 16 k-tiles per block
#define BLK_ROWS 128              // 4 waves * 32 rows

typedef __attribute__((ext_vector_type(8)))  _Float16 half8;
typedef __attribute__((ext_vector_type(4)))  _Float16 half4;
typedef __attribute__((ext_vector_type(16))) float    f32x16;

#if __has_builtin(__builtin_amdgcn_exp2f)
#define EXP2(x) __builtin_amdgcn_exp2f(x)
#else
#define EXP2(x) exp2f(x)
#endif
#if __has_builtin(__builtin_amdgcn_logf)
#define LOG2(x) __builtin_amdgcn_logf(x)
#else
#define LOG2(x) log2f(x)
#endif

__device__ __forceinline__ void gload_lds16(const void* g, void* l) {
  __builtin_amdgcn_global_load_lds(
      (const __attribute__((address_space(1))) unsigned int*)g,
      (__attribute__((address_space(3))) unsigned int*)l, 16, 0, 0);
}

// ---- fp32 -> f16 conversion + per-row diagonal -----------------------------
// One wave covers exactly one row (64 lanes x 4 elems = 256 = C), so the
// diagonal q_i.k_i (f16-rounded operands, f32 accum) is a free wave-reduce.
__global__ void cvt_kernel(const float* __restrict__ q, const float* __restrict__ k,
                           _Float16* __restrict__ qh, _Float16* __restrict__ kh,
                           float* __restrict__ pP) {
  const float QS = 20.60992915555663f;  // (1/0.07) * log2(e)
  int i = blockIdx.x * 256 + threadIdx.x;
  float4 qv = ((const float4*)q)[i];
  float4 kv = ((const float4*)k)[i];
  half4 qo, ko;
  qo[0] = (_Float16)(qv.x * QS); qo[1] = (_Float16)(qv.y * QS);
  qo[2] = (_Float16)(qv.z * QS); qo[3] = (_Float16)(qv.w * QS);
  ko[0] = (_Float16)kv.x; ko[1] = (_Float16)kv.y;
  ko[2] = (_Float16)kv.z; ko[3] = (_Float16)kv.w;
  ((half4*)qh)[i] = qo;
  ((half4*)kh)[i] = ko;

  float d = (float)qo[0] * (float)ko[0];
  d = fmaf((float)qo[1], (float)ko[1], d);
  d = fmaf((float)qo[2], (float)ko[2], d);
  d = fmaf((float)qo[3], (float)ko[3], d);
#pragma unroll
  for (int off = 1; off < 64; off <<= 1) d += __shfl_xor(d, off);
  if ((threadIdx.x & 63) == 0) pP[i >> 6] = d;   // row = global_thread / 64
}

// ---- main fused GEMM + per-lane online base-2 logsumexp --------------------
// Block: 256 threads = 4 waves; wave owns 32 rows via 32x32x16 MFMA.
// A layout: lane l holds q[row0 + (l&31)][ks*16 + (l>>5)*8 .. +8).
// B layout: lane l holds k[j0 + cf*32 + (l&31)][ks*16 + (l>>5)*8 .. +8).
// C/D layout (verified m74/m101): col = lane&31, row = (j&3)+8*(j>>2)+4*(l>>5).
// k-tile (64x256 f16 = 32 KiB) double-buffered; XOR-swizzled (16B chunk
// c at row r lives at slot c^(r&31)) -> conflict-free ds_read_b128.
__launch_bounds__(256, 2)
__global__ void sim_lse_kernel(const _Float16* __restrict__ qh,
                               const _Float16* __restrict__ kh,
                               float* __restrict__ pM,
                               float* __restrict__ pS) {
  __shared__ __align__(16) _Float16 kt[2 * BN * C_DIM];  // 64 KiB (2 buffers)
  const int tid  = threadIdx.x;
  const int lane = tid & 63;
  const int wave = tid >> 6;
  const int r    = lane & 31;
  const int hi   = lane >> 5;

  const int bid  = blockIdx.x;
  const int sp   = bid & (SPLIT - 1);  // XCD i (id%8) <- split i: k-slice L2-pinned
  const int rb   = bid >> 3;
  const int row0 = rb * BLK_ROWS + wave * 32;

  // A fragments resident for whole kernel: 16 x half8 = 64 VGPR
  half8 a[16];
  {
    const _Float16* qr = qh + (size_t)(row0 + r) * C_DIM + hi * 8;
#pragma unroll
    for (int ks = 0; ks < 16; ++ks) a[ks] = *(const half8*)(qr + ks * 16);
  }

  // Per-lane LSE state over this lane's (16 rows x 1 col-per-frag) outputs
  float M[16], S[16];
#pragma unroll
  for (int j = 0; j < 16; ++j) { M[j] = -__builtin_inff(); S[j] = 0.f; }

  // swizzled read base; addr = bb ^ (ks*32) gives chunk (2ks|hi)^r at row n
  const int bb0 = r * 512 + ((hi ^ r) << 4);       // col-frag 0: n = r
  const int bb1 = bb0 + 32 * 512;                  // col-frag 1: n = 32 + r

  const char* ksrc = (const char*)(kh + (size_t)sp * JCOLS * C_DIM);
  char* lds = (char*)kt;

  // ---- prologue: stage tile 0 into buffer 0 (swizzled source, linear dest)
#pragma unroll
  for (int it = 0; it < 8; ++it) {
    int linear = it * 4096 + tid * 16;
    int row = linear >> 9;                      // 512 B per k row
    int gc  = ((linear >> 4) & 31) ^ (row & 31);
    gload_lds16(ksrc + row * 512 + gc * 16, lds + linear);
  }

  for (int jt = 0; jt < JTILES; ++jt) {
    __syncthreads();  // own vmcnt drained before barrier => tile jt staged;
                      // prev tile's reads (lgkm) also drained => nxt reusable
    const char* cur = lds + (jt & 1) * 32768;

    // issue next tile's loads NOW; they land during compute below
    if (jt + 1 < JTILES) {
      const char* src = ksrc + (size_t)(jt + 1) * (BN * C_DIM * 2);
      char* nxt = lds + ((jt + 1) & 1) * 32768;
#pragma unroll
      for (int it = 0; it < 8; ++it) {
        int linear = it * 4096 + tid * 16;
        int row = linear >> 9;
        int gc  = ((linear >> 4) & 31) ^ (row & 31);
        gload_lds16(src + row * 512 + gc * 16, nxt + linear);
      }
    }

    // ---- 64-col tile: 16 K-steps x 2 col-frags; B-read feeds 32768 FLOP ---
    f32x16 acc0, acc1;
#pragma unroll
    for (int j = 0; j < 16; ++j) { acc0[j] = 0.f; acc1[j] = 0.f; }

#pragma unroll
    for (int ks = 0; ks < 16; ++ks) {
      half8 b0 = *(const half8*)(cur + (bb0 ^ (ks * 32)));
      half8 b1 = *(const half8*)(cur + (bb1 ^ (ks * 32)));
      acc0 = __builtin_amdgcn_mfma_f32_32x32x16_f16(a[ks], b0, acc0, 0, 0, 0);
      acc1 = __builtin_amdgcn_mfma_f32_32x32x16_f16(a[ks], b1, acc1, 0, 0, 0);
    }

    // ---- per-lane online logsumexp (base 2), no cross-lane traffic --------
#pragma unroll
    for (int j = 0; j < 16; ++j) {
      float v0 = acc0[j], v1 = acc1[j];
      float tmax  = fmaxf(v0, v1);
      float newM  = fmaxf(M[j], tmax);
      float alpha = EXP2(M[j] - newM);        // exp2(-inf)=0 handles init
      float p = EXP2(v0 - newM) + EXP2(v1 - newM);
      S[j] = fmaf(S[j], alpha, p);
      M[j] = newM;
    }
  }

  // ---- one-time butterfly merge across the 32 lanes of each half ----------
  // Lane group hi=0 (lanes 0..31) holds rows {(j&3)+8*(j>>2)}, hi=1 the +4
  // offset rows; offsets 1..16 stay within each 32-lane half.
#pragma unroll
  for (int j = 0; j < 16; ++j) {
#pragma unroll
    for (int off = 1; off < 32; off <<= 1) {
      float Mo = __shfl_xor(M[j], off);
      float So = __shfl_xor(S[j], off);
      float nm = fmaxf(M[j], Mo);
      S[j] = S[j] * EXP2(M[j] - nm) + So * EXP2(Mo - nm);
      M[j] = nm;
    }
  }

  if ((lane & 31) == 0) {   // lanes 0 and 32 write disjoint 16-row sets
#pragma unroll
    for (int j = 0; j < 16; ++j) {
      int grow = row0 + (j & 3) + 8 * (j >> 2) + 4 * hi;
      pM[(size_t)sp * N_ROWS + grow] = M[j];
      pS[(size_t)sp * N_ROWS + grow] = S[j];
    }
  }
}

// ---- stage 1: 32 blocks, one thread per row; partial sums -----------------
__global__ void finish1_kernel(const float* __restrict__ pM, const float* __restrict__ pS,
                               const float* __restrict__ pP, float* __restrict__ pPart) {
  const int tid = threadIdx.x;
  const int r = blockIdx.x * 256 + tid;
  float m = -__builtin_inff();
#pragma unroll
  for (int s = 0; s < SPLIT; ++s) m = fmaxf(m, pM[s * N_ROWS + r]);
  float ssum = 0.f;
#pragma unroll
  for (int s = 0; s < SPLIT; ++s)
    ssum = fmaf(pS[s * N_ROWS + r], EXP2(pM[s * N_ROWS + r] - m), ssum);
  float accl = (m + LOG2(ssum)) - pP[r];   // row loss in base-2 units
#pragma unroll
  for (int off = 1; off < 64; off <<= 1) accl += __shfl_xor(accl, off);
  __shared__ float wsum[4];
  if ((tid & 63) == 0) wsum[tid >> 6] = accl;
  __syncthreads();
  if (tid == 0)
    pPart[blockIdx.x] = wsum[0] + wsum[1] + wsum[2] + wsum[3];
}

// ---- stage 2: reduce 32 partials, convert base-2 -> nats, mean ------------
__global__ void finish2_kernel(const float* __restrict__ pPart, float* __restrict__ out) {
  const int tid = threadIdx.x;   // 64 threads
  float v = (tid < 32) ? pPart[tid] : 0.f;
#pragma unroll
  for (int off = 1; off < 64; off <<= 1) v += __shfl_xor(v, off);
  if (tid == 0)
    out[0] = v * (0.69314718055994531f / (float)N_ROWS);  // ln2 * mean
}

extern "C" void kernel_launch(void* const* d_in, const int* in_sizes, int n_in,
                              void* d_out, int out_size, void* d_ws, size_t ws_size,
                              hipStream_t stream) {
  const float* q = (const float*)d_in[0];
  const float* k = (const float*)d_in[1];
  float* out = (float*)d_out;
  char* ws = (char*)d_ws;

  _Float16* qh = (_Float16*)ws;                                  // 4 MiB
  _Float16* kh = (_Float16*)(ws + (size_t)N_ROWS * C_DIM * 2);   // 4 MiB
  float* pM = (float*)(ws + (size_t)N_ROWS * C_DIM * 4);         // 256 KiB
  float* pS = pM + SPLIT * N_ROWS;                               // 256 KiB
  float* pP = pS + SPLIT * N_ROWS;                               // 32 KiB
  float* pPart = pP + N_ROWS;                                    // 128 B

  cvt_kernel<<<dim3(N_ROWS * C_DIM / 4 / 256), dim3(256), 0, stream>>>(q, k, qh, kh, pP);
  sim_lse_kernel<<<dim3((N_ROWS / BLK_ROWS) * SPLIT), dim3(256), 0, stream>>>(qh, kh, pM, pS);
  finish1_kernel<<<dim3(N_ROWS / 256), dim3(256), 0, stream>>>(pM, pS, pP, pPart);
  finish2_kernel<<<dim3(1), dim3(64), 0, stream>>>(pPart, out);
}